// Round 14
// baseline (42.411 us; speedup 1.0000x reference)
//
#include <hip/hip_runtime.h>
#include <hip/hip_bf16.h>

// N=8192, D=128. loss = mean(-log(exp(sims_ii)) + 0.5*(log(den_i)+log(den_j)))
// sims = (A @ T^T) * exp(temp); den = row/col sums of exp(sims), diag zeroed.
//
// R14 = R10 best (33.95us) + coalesced Pj stores (transposed [rs][col] layout,
// 16x fewer store transactions) + phase-pair-batched csum tails (+4 regs) +
// transposing 64-row finalize blocks + 1-wave reduce.
// Failed theories (do not retry): R9 finer phases; R11 cs[16] deferral (regs);
// R12 last-block atomic (67us bomb); R13 LDS staging (ds latency > L1 reuse).
//
// ws layout (bytes):
//   [0,      1 MiB)  A fp8 e4m3 * exp(temp)*log2e, [r16][lane][32B]
//   [1 MiB,  2 MiB)  T fp8 e4m3, same layout, unscaled
//   [2 MiB,  3 MiB)  den_i partials float[8192][32]   (Pi[row][j])
//   [4 MiB,  8 MiB)  den_j partials float[128][8192]  (Pj[rs][col] TRANSPOSED)
//   [8 MiB, +512 B)  block losses float[128]

typedef __attribute__((ext_vector_type(8))) int   v8i;
typedef __attribute__((ext_vector_type(4))) float f32x4;

#define SCALE_ONE 0x7F7F7F7F   // e8m0 1.0 in every byte (opsel-proof)

__device__ __forceinline__ float fast_exp2(float x) {
#if __has_builtin(__builtin_amdgcn_exp2f)
    return __builtin_amdgcn_exp2f(x);      // bare v_exp_f32
#else
    return __expf(x * 0.69314718056f);
#endif
}

// VALU-pipe partial-sum step (HW-verified R4-R13): after 1,2,4,8 lane 15 of
// each 16-lane row holds the 16-lane sum (0-filled at edges).
template <int CTRL>
__device__ __forceinline__ float dpp_sr_add(float v) {
    int s = __builtin_amdgcn_update_dpp(0, __float_as_int(v), CTRL, 0xf, 0xf, true);
    return v + __int_as_float(s);
}
__device__ __forceinline__ float row16_sum(float v) {
    v = dpp_sr_add<0x111>(v);   // row_shr:1
    v = dpp_sr_add<0x112>(v);   // row_shr:2
    v = dpp_sr_add<0x114>(v);   // row_shr:4
    v = dpp_sr_add<0x118>(v);   // row_shr:8
    return v;                   // valid in lane 15 of each 16-lane row
}

// ---------------------------------------------------------------- kernel 1
// fp8 fragment-major pack for mfma_scale 16x16x128 (R8-R13 verified):
//   lane l of tile r16 holds M[r16*16 + (l&15)][(l>>4)*32 .. +32]  (32 B).
// A pre-scaled by exp(temp)*log2(e); T unscaled.
__global__ void convert_pack(const float* __restrict__ a,
                             const float* __restrict__ t,
                             const float* __restrict__ temps,
                             unsigned char* __restrict__ oa,
                             unsigned char* __restrict__ ot) {
    int idx = blockIdx.x * 256 + threadIdx.x;          // 0 .. 131071
    const bool isT = (idx >> 16) != 0;
    const float* src = isT ? t : a;
    unsigned char* dst = isT ? ot : oa;
    const float s = isT ? 1.0f : (__expf(temps[0]) * 1.44269504f);
    int loc = idx & 65535;
    int tile = loc >> 7, sub = loc & 127;
    int lane = sub >> 1, h = sub & 1;
    int row = tile * 16 + (lane & 15);
    int k0  = (lane >> 4) * 32 + h * 16;
    const float4* s4 = reinterpret_cast<const float4*>(src + row * 128 + k0);
    unsigned w[4];
#pragma unroll
    for (int q = 0; q < 4; ++q) {
        float4 f = s4[q];
        int v = __builtin_amdgcn_cvt_pk_fp8_f32(f.x * s, f.y * s, 0, false);
        v = __builtin_amdgcn_cvt_pk_fp8_f32(f.z * s, f.w * s, v, true);
        w[q] = (unsigned)v;
    }
    *reinterpret_cast<uint4*>(dst + tile * 2048 + lane * 32 + h * 16) =
        make_uint4(w[0], w[1], w[2], w[3]);
}

// ---------------------------------------------------------------- kernel 2
// Independent 64x256 wave-tiles, zero LDS, zero barriers (R10 pattern).
// af[4] pinned; B dual-buffered one 32-col phase ahead. Phases leave their
// per-lane col partials in csA/csB; every 2 phases one TAIL4 does 4
// independent shfl chains (latency pipelined) + 4 coalesced 64B stores
// into the TRANSPOSED Pj[rs][col].
#define LD2(BUF, T0)                                                     \
    BUF[0] = *reinterpret_cast<const v8i*>(tb + (T0) * 2048);            \
    BUF[1] = *reinterpret_cast<const v8i*>(tb + (T0 + 1) * 2048);

#define PH(BF, CS)                                                       \
  {                                                                      \
    f32x4 acc[4][2];                                                     \
    _Pragma("unroll") for (int m = 0; m < 4; ++m)                        \
      _Pragma("unroll") for (int n = 0; n < 2; ++n)                      \
        acc[m][n] = (f32x4){0.f, 0.f, 0.f, 0.f};                         \
    _Pragma("unroll") for (int m = 0; m < 4; ++m)                        \
      _Pragma("unroll") for (int n = 0; n < 2; ++n)                      \
        acc[m][n] = __builtin_amdgcn_mfma_scale_f32_16x16x128_f8f6f4(    \
            af[m], BF[n], acc[m][n], 0, 0, 0, SCALE_ONE, 0, SCALE_ONE);  \
    CS[0] = 0.f; CS[1] = 0.f;                                            \
    _Pragma("unroll") for (int m = 0; m < 4; ++m)                        \
      _Pragma("unroll") for (int n = 0; n < 2; ++n)                      \
        _Pragma("unroll") for (int jj = 0; jj < 4; ++jj) {               \
          float v = fast_exp2(acc[m][n][jj]);                            \
          rsum[m][jj] += v;                                              \
          CS[n] += v;                                                    \
        }                                                                \
  }

#define TAIL4(BASE)                                                      \
  {                                                                      \
    float t0 = csA[0], t1 = csA[1], t2 = csB[0], t3 = csB[1];            \
    t0 += __shfl_xor(t0, 16); t1 += __shfl_xor(t1, 16);                  \
    t2 += __shfl_xor(t2, 16); t3 += __shfl_xor(t3, 16);                  \
    t0 += __shfl_xor(t0, 32); t1 += __shfl_xor(t1, 32);                  \
    t2 += __shfl_xor(t2, 32); t3 += __shfl_xor(t3, 32);                  \
    if (lane < 16) {                                                     \
      pjb[((BASE) + 0) * 16 + lcol] = t0;                                \
      pjb[((BASE) + 1) * 16 + lcol] = t1;                                \
      pjb[((BASE) + 2) * 16 + lcol] = t2;                                \
      pjb[((BASE) + 3) * 16 + lcol] = t3;                                \
    }                                                                    \
  }

__global__ void __launch_bounds__(256)
gemm_exp(const unsigned char* __restrict__ Ap, const unsigned char* __restrict__ Tp,
         float* __restrict__ Pi, float* __restrict__ Pj) {
    const int tid = threadIdx.x;
    const int wave = tid >> 6, lane = tid & 63;
    const int krow = lane >> 4, lcol = lane & 15;
    const int fid = blockIdx.x;                        // 0..1023
    const int vid = (fid & 7) * 128 + (fid >> 3);      // bijective (1024%8==0)
    const int j  = vid >> 5;                           // col-strip (256 cols) 0..31
    const int rg = vid & 31;                           // row-group (256 rows) 0..31
    const int rs = rg * 4 + wave;                      // row-strip (64 rows) 0..127

    // A fragments: 4 x 32B/lane coalesced loads, held for all 8 phases
    v8i af[4];
#pragma unroll
    for (int m = 0; m < 4; ++m)
        af[m] = *reinterpret_cast<const v8i*>(Ap + (rs * 4 + m) * 2048 + lane * 32);

    const unsigned char* tb = Tp + j * 16 * 2048 + lane * 32;  // 16 tiles/strip
    float* pjb = Pj + rs * 8192 + j * 256;             // this wave's Pj row seg

    float rsum[4][4] = {};
    float csA[2], csB[2];
    v8i bfA[2], bfB[2];

    LD2(bfA, 0)
    LD2(bfB, 2)
    PH(bfA, csA)             // tiles 0,1
    LD2(bfA, 4)
    PH(bfB, csB)             // tiles 2,3
    TAIL4(0)
    LD2(bfB, 6)
    PH(bfA, csA)             // tiles 4,5
    LD2(bfA, 8)
    PH(bfB, csB)             // tiles 6,7
    TAIL4(4)
    LD2(bfB, 10)
    PH(bfA, csA)             // tiles 8,9
    LD2(bfA, 12)
    PH(bfB, csB)             // tiles 10,11
    TAIL4(8)
    LD2(bfB, 14)
    PH(bfA, csA)             // tiles 12,13
    PH(bfB, csB)             // tiles 14,15
    TAIL4(12)

    // row sums over this wave's 256 cols: DPP reduce, lane 15 of each krow row
#pragma unroll
    for (int m = 0; m < 4; ++m)
#pragma unroll
        for (int jj = 0; jj < 4; ++jj) {
            float v = row16_sum(rsum[m][jj]);
            if (lcol == 15) {
                int row = rs * 64 + m * 16 + krow * 4 + jj;
                Pi[row * 32 + j] = v;
            }
        }
}

// ---------------------------------------------------------------- kernel 3
// 128 blocks x 64 rows. Pj[rs][col] read fully coalesced (256B/wave/step);
// Pi + diag per row via 4-thread groups; diag fp32-exact. One block sum out.
__global__ void finalize_rows(const float* __restrict__ a, const float* __restrict__ t,
                              const float* __restrict__ temps,
                              const float* __restrict__ Pi, const float* __restrict__ Pj,
                              float* __restrict__ blockLoss) {
    __shared__ float ldsJ[4][64];
    __shared__ float wsum[4];
    const int tid = threadIdx.x;                       // 256
    const int r0 = blockIdx.x * 64;
    const float sc = __expf(temps[0]);

    // denj partials: wave g sums rs in [g*32, g*32+32), cols r0..r0+63
    {
        const int c = tid & 63, g = tid >> 6;
        float dj = 0.f;
#pragma unroll 4
        for (int rr = 0; rr < 32; ++rr)
            dj += Pj[(g * 32 + rr) * 8192 + r0 + c];
        ldsJ[g][c] = dj;
    }
    __syncthreads();

    // per-row: 4 threads per row (q = tid&3), row = r0 + tid/4
    const int row = r0 + (tid >> 2), q = tid & 3;
    const float4* pi4 = reinterpret_cast<const float4*>(Pi + row * 32 + q * 8);
    float4 p0 = pi4[0], p1 = pi4[1];
    float deni = (p0.x + p0.y + p0.z + p0.w) + (p1.x + p1.y + p1.z + p1.w);
    float dotp = 0.f;
    const float4* a4 = reinterpret_cast<const float4*>(a + row * 128 + q * 32);
    const float4* t4 = reinterpret_cast<const float4*>(t + row * 128 + q * 32);
#pragma unroll
    for (int u = 0; u < 8; ++u) {
        float4 av = a4[u], tv = t4[u];
        dotp += av.x * tv.x + av.y * tv.y + av.z * tv.z + av.w * tv.w;
    }
    deni += __shfl_xor(deni, 1); deni += __shfl_xor(deni, 2);
    dotp += __shfl_xor(dotp, 1); dotp += __shfl_xor(dotp, 2);

    float loss = 0.f;
    if (q == 0) {
        float denj = (ldsJ[0][row - r0] + ldsJ[1][row - r0])
                   + (ldsJ[2][row - r0] + ldsJ[3][row - r0]);
        float diag = __expf(sc * dotp);
        float di = fmaxf(deni - diag, 1e-20f);
        float dj = fmaxf(denj - diag, 1e-20f);
        loss = -sc * dotp + 0.5f * (__logf(di) + __logf(dj));
    }
#pragma unroll
    for (int m = 1; m < 64; m <<= 1) loss += __shfl_xor(loss, m);
    if ((tid & 63) == 0) wsum[tid >> 6] = loss;
    __syncthreads();
    if (tid == 0)
        blockLoss[blockIdx.x] = (wsum[0] + wsum[1]) + (wsum[2] + wsum[3]);
}

// ---------------------------------------------------------------- kernel 4
__global__ void reduce_loss(const float* __restrict__ blockLoss, float* __restrict__ out) {
    const int tid = threadIdx.x;   // 64
    float s = blockLoss[tid] + blockLoss[tid + 64];
#pragma unroll
    for (int m = 1; m < 64; m <<= 1) s += __shfl_xor(s, m);
    if (tid == 0) out[0] = s * (1.0f / 8192.0f);
}

extern "C" void kernel_launch(void* const* d_in, const int* in_sizes, int n_in,
                              void* d_out, int out_size, void* d_ws, size_t ws_size,
                              hipStream_t stream) {
    const float* a     = (const float*)d_in[0];
    const float* t     = (const float*)d_in[1];
    const float* temps = (const float*)d_in[2];
    float* out = (float*)d_out;

    char* ws = (char*)d_ws;
    unsigned char* Ap = (unsigned char*)(ws);
    unsigned char* Tp = (unsigned char*)(ws + (1u << 20));
    float* Pi  = (float*)(ws + (2u << 20));
    float* Pj  = (float*)(ws + (4u << 20));
    float* bl  = (float*)(ws + (8u << 20));

    convert_pack<<<512, 256, 0, stream>>>(a, t, temps, Ap, Tp);
    gemm_exp<<<1024, 256, 0, stream>>>(Ap, Tp, Pi, Pj);
    finalize_rows<<<128, 256, 0, stream>>>(a, t, temps, Pi, Pj, bl);
    reduce_loss<<<1, 64, 0, stream>>>(bl, out);
}

// Round 15
// 34.101 us; speedup vs baseline: 1.2437x; 1.2437x over previous
//
#include <hip/hip_runtime.h>
#include <hip/hip_bf16.h>

// N=8192, D=128. loss = mean(-log(exp(sims_ii)) + 0.5*(log(den_i)+log(den_j)))
// sims = (A @ T^T) * exp(temp); den = row/col sums of exp(sims), diag zeroed.
//
// R15 = exact revert to the 33.95us best (R10 spine: fp8 MX K=128, 64x256
// independent wave-tiles, dual-buffered B, zero LDS, zero barriers) plus two
// PHASE-local micro-changes: (1) tree-summed col partials (cuts a 16-deep
// serial FADD chain to depth 4); (2) s_setprio(1) around the MFMA cluster
// (T5; our waves are independent/desynced like attn where it paid +4-7%).
// Failed-theory bank (do not retry): R9 finer phases; R11 cs[16] deferral;
// R12 last-block atomic; R13 LDS-staged B; R14 Pj transpose + 128-blk final.
//
// ws layout (bytes):
//   [0,      1 MiB)  A fp8 e4m3 * exp(temp)*log2e, [r16][lane][32B]
//   [1 MiB,  2 MiB)  T fp8 e4m3, same layout, unscaled
//   [2 MiB,  3 MiB)  den_i partials float[8192][32]   (slot = col-strip j)
//   [4 MiB,  8 MiB)  den_j partials float[8192][128]  (slot = row-strip rs)
//   [8 MiB, +32 KiB) per-row loss float[8192]

typedef __attribute__((ext_vector_type(8))) int   v8i;
typedef __attribute__((ext_vector_type(4))) float f32x4;

#define SCALE_ONE 0x7F7F7F7F   // e8m0 1.0 in every byte (opsel-proof)

__device__ __forceinline__ float fast_exp2(float x) {
#if __has_builtin(__builtin_amdgcn_exp2f)
    return __builtin_amdgcn_exp2f(x);      // bare v_exp_f32
#else
    return __expf(x * 0.69314718056f);
#endif
}

// VALU-pipe partial-sum step (HW-verified R4-R14): after 1,2,4,8 lane 15 of
// each 16-lane row holds the 16-lane sum (0-filled at edges).
template <int CTRL>
__device__ __forceinline__ float dpp_sr_add(float v) {
    int s = __builtin_amdgcn_update_dpp(0, __float_as_int(v), CTRL, 0xf, 0xf, true);
    return v + __int_as_float(s);
}
__device__ __forceinline__ float row16_sum(float v) {
    v = dpp_sr_add<0x111>(v);   // row_shr:1
    v = dpp_sr_add<0x112>(v);   // row_shr:2
    v = dpp_sr_add<0x114>(v);   // row_shr:4
    v = dpp_sr_add<0x118>(v);   // row_shr:8
    return v;                   // valid in lane 15 of each 16-lane row
}

// ---------------------------------------------------------------- kernel 1
// fp8 fragment-major pack for mfma_scale 16x16x128 (R8-R14 verified):
//   lane l of tile r16 holds M[r16*16 + (l&15)][(l>>4)*32 .. +32]  (32 B).
// A pre-scaled by exp(temp)*log2(e); T unscaled.
__global__ void convert_pack(const float* __restrict__ a,
                             const float* __restrict__ t,
                             const float* __restrict__ temps,
                             unsigned char* __restrict__ oa,
                             unsigned char* __restrict__ ot) {
    int idx = blockIdx.x * 256 + threadIdx.x;          // 0 .. 131071
    const bool isT = (idx >> 16) != 0;
    const float* src = isT ? t : a;
    unsigned char* dst = isT ? ot : oa;
    const float s = isT ? 1.0f : (__expf(temps[0]) * 1.44269504f);
    int loc = idx & 65535;
    int tile = loc >> 7, sub = loc & 127;
    int lane = sub >> 1, h = sub & 1;
    int row = tile * 16 + (lane & 15);
    int k0  = (lane >> 4) * 32 + h * 16;
    const float4* s4 = reinterpret_cast<const float4*>(src + row * 128 + k0);
    unsigned w[4];
#pragma unroll
    for (int q = 0; q < 4; ++q) {
        float4 f = s4[q];
        int v = __builtin_amdgcn_cvt_pk_fp8_f32(f.x * s, f.y * s, 0, false);
        v = __builtin_amdgcn_cvt_pk_fp8_f32(f.z * s, f.w * s, v, true);
        w[q] = (unsigned)v;
    }
    *reinterpret_cast<uint4*>(dst + tile * 2048 + lane * 32 + h * 16) =
        make_uint4(w[0], w[1], w[2], w[3]);
}

// ---------------------------------------------------------------- kernel 2
// Independent 64x256 wave-tiles, zero LDS, zero barriers (R10 pattern,
// 33.95us verified). af[4] pinned; B dual-buffered one 32-col phase ahead.
// 8 phases x (2 loads, 8 mfma K=128 under setprio(1), 32 exp2, tree csum,
// in-phase shfl tail + store).
#define LD2(BUF, T0)                                                     \
    BUF[0] = *reinterpret_cast<const v8i*>(tb + (T0) * 2048);            \
    BUF[1] = *reinterpret_cast<const v8i*>(tb + (T0 + 1) * 2048);

#define PHASE(BF, COLBASE)                                               \
  {                                                                      \
    f32x4 acc[4][2];                                                     \
    _Pragma("unroll") for (int m = 0; m < 4; ++m)                        \
      _Pragma("unroll") for (int n = 0; n < 2; ++n)                      \
        acc[m][n] = (f32x4){0.f, 0.f, 0.f, 0.f};                         \
    __builtin_amdgcn_s_setprio(1);                                       \
    _Pragma("unroll") for (int m = 0; m < 4; ++m)                        \
      _Pragma("unroll") for (int n = 0; n < 2; ++n)                      \
        acc[m][n] = __builtin_amdgcn_mfma_scale_f32_16x16x128_f8f6f4(    \
            af[m], BF[n], acc[m][n], 0, 0, 0, SCALE_ONE, 0, SCALE_ONE);  \
    __builtin_amdgcn_s_setprio(0);                                       \
    _Pragma("unroll") for (int n = 0; n < 2; ++n) {                      \
      float cm[4];                                                       \
      _Pragma("unroll") for (int m = 0; m < 4; ++m) {                    \
        float v0 = fast_exp2(acc[m][n][0]);                              \
        float v1 = fast_exp2(acc[m][n][1]);                              \
        float v2 = fast_exp2(acc[m][n][2]);                              \
        float v3 = fast_exp2(acc[m][n][3]);                              \
        rsum[m][0] += v0; rsum[m][1] += v1;                              \
        rsum[m][2] += v2; rsum[m][3] += v3;                              \
        cm[m] = (v0 + v1) + (v2 + v3);                                   \
      }                                                                  \
      float v = (cm[0] + cm[1]) + (cm[2] + cm[3]);                       \
      v += __shfl_xor(v, 16); v += __shfl_xor(v, 32);                    \
      if (lane < 16) {                                                   \
        int col = (COLBASE + n) * 16 + lcol;                             \
        Pj[col * 128 + rs] = v;                                          \
      }                                                                  \
    }                                                                    \
  }

__global__ void __launch_bounds__(256)
gemm_exp(const unsigned char* __restrict__ Ap, const unsigned char* __restrict__ Tp,
         float* __restrict__ Pi, float* __restrict__ Pj) {
    const int tid = threadIdx.x;
    const int wave = tid >> 6, lane = tid & 63;
    const int krow = lane >> 4, lcol = lane & 15;
    const int fid = blockIdx.x;                        // 0..1023
    const int vid = (fid & 7) * 128 + (fid >> 3);      // bijective (1024%8==0)
    const int j  = vid >> 5;                           // col-strip (256 cols) 0..31
    const int rg = vid & 31;                           // row-group (256 rows) 0..31
    const int rs = rg * 4 + wave;                      // row-strip (64 rows) 0..127

    // A fragments: 4 x 32B/lane coalesced loads, held for all 8 phases
    v8i af[4];
#pragma unroll
    for (int m = 0; m < 4; ++m)
        af[m] = *reinterpret_cast<const v8i*>(Ap + (rs * 4 + m) * 2048 + lane * 32);

    const unsigned char* tb = Tp + j * 16 * 2048 + lane * 32;  // 16 tiles/strip

    float rsum[4][4] = {};
    v8i bfA[2], bfB[2];

    // prologue: phase-0 B (16-col tiles 0,1)
    bfA[0] = *reinterpret_cast<const v8i*>(tb);
    bfA[1] = *reinterpret_cast<const v8i*>(tb + 2048);

#pragma unroll 1
    for (int ph2 = 0; ph2 < 4; ++ph2) {
        const unsigned char* base = tb + ph2 * 8192;   // 4 tiles per iteration

        // prefetch odd phase (tiles +2,+3) — covered by PHASE(bfA)
        bfB[0] = *reinterpret_cast<const v8i*>(base + 2 * 2048);
        bfB[1] = *reinterpret_cast<const v8i*>(base + 3 * 2048);

        PHASE(bfA, j * 16 + ph2 * 4);

        // prefetch next even phase — covered by PHASE(bfB)
        if (ph2 < 3) {
            bfA[0] = *reinterpret_cast<const v8i*>(base + 8192);
            bfA[1] = *reinterpret_cast<const v8i*>(base + 8192 + 2048);
        }

        PHASE(bfB, j * 16 + ph2 * 4 + 2);
    }

    // row sums over this wave's 256 cols: DPP reduce, lane 15 of each krow row
#pragma unroll
    for (int m = 0; m < 4; ++m)
#pragma unroll
        for (int jj = 0; jj < 4; ++jj) {
            float v = row16_sum(rsum[m][jj]);
            if (lcol == 15) {
                int row = rs * 64 + m * 16 + krow * 4 + jj;
                Pi[row * 32 + j] = v;
            }
        }
}

// ---------------------------------------------------------------- kernel 3
// One wave per row, 4 rows/block; diag dot recomputed in fp32 (exact
// numerator), subtracted from both fp8-derived denominators.
__global__ void finalize_rows(const float* __restrict__ a, const float* __restrict__ t,
                              const float* __restrict__ temps,
                              const float* __restrict__ Pi, const float* __restrict__ Pj,
                              float* __restrict__ loss) {
    const int r = blockIdx.x * 4 + (threadIdx.x >> 6);
    const int l = threadIdx.x & 63;
    const float sc = __expf(temps[0]);
    float deni = (l < 32) ? Pi[r * 32 + l] : 0.f;
    float denj = Pj[r * 128 + l] + Pj[r * 128 + 64 + l];
    float dotp = a[r * 128 + l] * t[r * 128 + l]
               + a[r * 128 + 64 + l] * t[r * 128 + 64 + l];
#pragma unroll
    for (int m = 1; m < 64; m <<= 1) {
        deni += __shfl_xor(deni, m);
        denj += __shfl_xor(denj, m);
        dotp += __shfl_xor(dotp, m);
    }
    if (l == 0) {
        float diag = __expf(sc * dotp);
        float di = fmaxf(deni - diag, 1e-20f);
        float dj = fmaxf(denj - diag, 1e-20f);
        loss[r] = -sc * dotp + 0.5f * (__logf(di) + __logf(dj));
    }
}

// ---------------------------------------------------------------- kernel 4
__global__ void reduce_loss(const float* __restrict__ loss, float* __restrict__ out) {
    __shared__ float wsum[16];
    const int tid = threadIdx.x;   // 1024
    float s = 0.f;
#pragma unroll
    for (int i = 0; i < 8; ++i) s += loss[tid + i * 1024];
#pragma unroll
    for (int m = 1; m < 64; m <<= 1) s += __shfl_xor(s, m);
    if ((tid & 63) == 0) wsum[tid >> 6] = s;
    __syncthreads();
    if (tid == 0) {
        float acc = 0.f;
#pragma unroll
        for (int w = 0; w < 16; ++w) acc += wsum[w];
        out[0] = acc * (1.0f / 8192.0f);
    }
}

extern "C" void kernel_launch(void* const* d_in, const int* in_sizes, int n_in,
                              void* d_out, int out_size, void* d_ws, size_t ws_size,
                              hipStream_t stream) {
    const float* a     = (const float*)d_in[0];
    const float* t     = (const float*)d_in[1];
    const float* temps = (const float*)d_in[2];
    float* out = (float*)d_out;

    char* ws = (char*)d_ws;
    unsigned char* Ap = (unsigned char*)(ws);
    unsigned char* Tp = (unsigned char*)(ws + (1u << 20));
    float* Pi  = (float*)(ws + (2u << 20));
    float* Pj  = (float*)(ws + (4u << 20));
    float* los = (float*)(ws + (8u << 20));

    convert_pack<<<512, 256, 0, stream>>>(a, t, temps, Ap, Tp);
    gemm_exp<<<1024, 256, 0, stream>>>(Ap, Tp, Pi, Pj);
    finalize_rows<<<2048, 256, 0, stream>>>(a, t, temps, Pi, Pj, los);
    reduce_loss<<<1, 1024, 0, stream>>>(los, out);
}